// Round 3
// baseline (83.689 us; speedup 1.0000x reference)
//
#include <hip/hip_runtime.h>
#include <cstddef>
#include <cmath>

#define SEQ    1024
#define CH     64
#define UNITS  32
#define WIDTH  64
#define HALFW  32
#define BATCH  4
#define EPS    1e-7f

#define TS     8          // s-rows per block
#define TT     80         // staged t-extent (need sl+j <= 70)
#define XTS    68         // xT row stride (words), mult of 4, mod 32 = 4
#define KTS    36         // kT/qT row stride, mult of 4, mod 32 = 4
#define SCS    68         // sc row stride
#define VTS    68         // vt row stride

// ---------------- Kernel 1: q' = x.Wt^T + bh, k = x.Wx^T ----------------
__global__ __launch_bounds__(256) void qk_kernel(
    const float* __restrict__ x, const float* __restrict__ Wt,
    const float* __restrict__ Wx, const float* __restrict__ bh,
    float* __restrict__ q, float* __restrict__ k)
{
    int bu = blockIdx.x;                 // b*UNITS + u
    int u  = bu & (UNITS - 1);
    int b  = bu >> 5;
    int s4 = (int)threadIdx.x << 2;

    const float* wt = Wt + u * CH;
    const float* wx = Wx + u * CH;
    const float* xb = x + (size_t)b * CH * SEQ + s4;

    float4 qa = {0.f, 0.f, 0.f, 0.f};
    float4 ka = {0.f, 0.f, 0.f, 0.f};
#pragma unroll
    for (int c = 0; c < CH; ++c) {
        float4 xv = *reinterpret_cast<const float4*>(xb + (size_t)c * SEQ);
        float wtc = wt[c], wxc = wx[c];
        qa.x = fmaf(xv.x, wtc, qa.x); qa.y = fmaf(xv.y, wtc, qa.y);
        qa.z = fmaf(xv.z, wtc, qa.z); qa.w = fmaf(xv.w, wtc, qa.w);
        ka.x = fmaf(xv.x, wxc, ka.x); ka.y = fmaf(xv.y, wxc, ka.y);
        ka.z = fmaf(xv.z, wxc, ka.z); ka.w = fmaf(xv.w, wxc, ka.w);
    }
    float bv = bh[u];
    qa.x += bv; qa.y += bv; qa.z += bv; qa.w += bv;
    size_t o = (size_t)bu * SEQ + s4;
    *reinterpret_cast<float4*>(q + o) = qa;
    *reinterpret_cast<float4*>(k + o) = ka;
}

// ---------------- Kernel 2: scores + softmax + a-write + v --------------
// All LDS tiles transposed (t-major) so band-shifted accesses stay 16B
// aligned and vectorize to ds_read_b128 along the c / u dimension.
__global__ __launch_bounds__(256) void attn_kernel(
    const float* __restrict__ x,
    const float* __restrict__ qp, const float* __restrict__ k,
    const float* __restrict__ Wa_w, const float* __restrict__ Wa_b,
    float* __restrict__ out)
{
    __shared__ __align__(16) float xT[TT * XTS];    // xT[tt][c]
    __shared__ __align__(16) float kT[TT * KTS];    // kT[tt][u]
    __shared__ __align__(16) float qT[TS * KTS];    // qT[sl][u] (bh folded)
    __shared__ __align__(16) float sc[TS * SCS];    // a[sl][j]
    __shared__ __align__(16) float vt[TS * VTS];    // v[sl][c]
    __shared__ __align__(16) float wa_s[UNITS];
    __shared__ float wab_s;

    int tid = threadIdx.x;
    int blk = blockIdx.x;
    int b   = blk >> 7;                 // 128 tiles per batch
    int s0  = (blk & 127) << 3;
    int t0  = s0 - HALFW;

    const float* xb = x  + (size_t)b * CH * SEQ;
    const float* qb = qp + (size_t)b * UNITS * SEQ;
    const float* kb = k  + (size_t)b * UNITS * SEQ;

    // ---- stage xT: 80 tt x 16 cg = 1280 b128 slots ----
#pragma unroll
    for (int i = 0; i < 5; ++i) {
        int idx = i * 256 + tid;
        int cg = idx / TT;
        int tt = idx - cg * TT;
        int t = t0 + tt; t = t < 0 ? 0 : (t > SEQ - 1 ? SEQ - 1 : t);
        float4 v4;
        v4.x = xb[(4 * cg + 0) * SEQ + t];
        v4.y = xb[(4 * cg + 1) * SEQ + t];
        v4.z = xb[(4 * cg + 2) * SEQ + t];
        v4.w = xb[(4 * cg + 3) * SEQ + t];
        *reinterpret_cast<float4*>(&xT[tt * XTS + 4 * cg]) = v4;
    }
    // ---- stage kT: 80 tt x 8 uq = 640 slots ----
#pragma unroll
    for (int i = 0; i < 3; ++i) {
        int idx = i * 256 + tid;
        if (idx < TT * (UNITS / 4)) {
            int uq = idx / TT;
            int tt = idx - uq * TT;
            int t = t0 + tt; t = t < 0 ? 0 : (t > SEQ - 1 ? SEQ - 1 : t);
            float4 v4;
            v4.x = kb[(4 * uq + 0) * SEQ + t];
            v4.y = kb[(4 * uq + 1) * SEQ + t];
            v4.z = kb[(4 * uq + 2) * SEQ + t];
            v4.w = kb[(4 * uq + 3) * SEQ + t];
            *reinterpret_cast<float4*>(&kT[tt * KTS + 4 * uq]) = v4;
        }
    }
    // ---- stage qT: 8 sl x 8 uq ----
    if (tid < 64) {
        int sl = tid >> 3, uq = tid & 7;
        float4 v4;
        v4.x = qb[(4 * uq + 0) * SEQ + s0 + sl];
        v4.y = qb[(4 * uq + 1) * SEQ + s0 + sl];
        v4.z = qb[(4 * uq + 2) * SEQ + s0 + sl];
        v4.w = qb[(4 * uq + 3) * SEQ + s0 + sl];
        *reinterpret_cast<float4*>(&qT[sl * KTS + 4 * uq]) = v4;
    }
    if (tid < UNITS) wa_s[tid] = Wa_w[tid];
    if (tid == 0)    wab_s = Wa_b[0];
    __syncthreads();

    // ---- scores + softmax: 128 threads, thread -> (sl, 4 j's) ----
    if (tid < 128) {
        int sl = tid >> 4, tq = tid & 15;
        int j0 = 4 * tq;
        float e0 = wab_s, e1 = wab_s, e2 = wab_s, e3 = wab_s;
#pragma unroll
        for (int uq = 0; uq < 8; ++uq) {
            float4 q4 = *reinterpret_cast<const float4*>(&qT[sl * KTS + 4 * uq]);
            float4 w4 = *reinterpret_cast<const float4*>(&wa_s[4 * uq]);
#pragma unroll
            for (int e = 0; e < 4; ++e) {
                float4 k4 = *reinterpret_cast<const float4*>(
                    &kT[(sl + j0 + e) * KTS + 4 * uq]);
                float z0 = q4.x + k4.x, z1 = q4.y + k4.y;
                float z2 = q4.z + k4.z, z3 = q4.w + k4.w;
                float t0f = 1.f - 2.f * __builtin_amdgcn_rcpf(__expf(2.f * z0) + 1.f);
                float t1f = 1.f - 2.f * __builtin_amdgcn_rcpf(__expf(2.f * z1) + 1.f);
                float t2f = 1.f - 2.f * __builtin_amdgcn_rcpf(__expf(2.f * z2) + 1.f);
                float t3f = 1.f - 2.f * __builtin_amdgcn_rcpf(__expf(2.f * z3) + 1.f);
                float acc = fmaf(t0f, w4.x, fmaf(t1f, w4.y,
                            fmaf(t2f, w4.z, t3f * w4.w)));
                if      (e == 0) e0 += acc;
                else if (e == 1) e1 += acc;
                else if (e == 2) e2 += acc;
                else             e3 += acc;
            }
        }
        int tb = t0 + sl + j0;
        if (tb + 0 < 0 || tb + 0 >= SEQ) e0 = -INFINITY;
        if (tb + 1 < 0 || tb + 1 >= SEQ) e1 = -INFINITY;
        if (tb + 2 < 0 || tb + 2 >= SEQ) e2 = -INFINITY;
        if (tb + 3 < 0 || tb + 3 >= SEQ) e3 = -INFINITY;

        float m = fmaxf(fmaxf(e0, e1), fmaxf(e2, e3));
#pragma unroll
        for (int off = 8; off >= 1; off >>= 1) m = fmaxf(m, __shfl_xor(m, off));
        float p0 = __expf(e0 - m), p1 = __expf(e1 - m);
        float p2 = __expf(e2 - m), p3 = __expf(e3 - m);
        float ssum = (p0 + p1) + (p2 + p3);
#pragma unroll
        for (int off = 8; off >= 1; off >>= 1) ssum += __shfl_xor(ssum, off);
        float inv = __builtin_amdgcn_rcpf(ssum + EPS);
        float4 a4 = {p0 * inv, p1 * inv, p2 * inv, p3 * inv};
        *reinterpret_cast<float4*>(&sc[sl * SCS + j0]) = a4;
    }
    __syncthreads();

    // ---- v halves: thread -> (jh, sl, cg), 32 j each ----
    int jh  = tid >> 7;
    int r   = tid & 127;
    int slv = r >> 4;
    int cg  = r & 15;
    float4 acc = {0.f, 0.f, 0.f, 0.f};
#pragma unroll 8
    for (int jj = 0; jj < 32; ++jj) {
        int j = jh * 32 + jj;
        float a = sc[slv * SCS + j];
        float4 x4 = *reinterpret_cast<const float4*>(
            &xT[(slv + j) * XTS + 4 * cg]);
        acc.x = fmaf(a, x4.x, acc.x);
        acc.y = fmaf(a, x4.y, acc.y);
        acc.z = fmaf(a, x4.z, acc.z);
        acc.w = fmaf(a, x4.w, acc.w);
    }
    if (jh == 1)
        *reinterpret_cast<float4*>(&vt[slv * VTS + 4 * cg]) = acc;
    __syncthreads();

    if (jh == 0) {
        float4 p = *reinterpret_cast<const float4*>(&vt[slv * VTS + 4 * cg]);
        acc.x += p.x; acc.y += p.y; acc.z += p.z; acc.w += p.w;
        *reinterpret_cast<float4*>(&vt[slv * VTS + 4 * cg]) = acc;
    } else {
        // a-write: 8 rows x 256 float4 slots = 2048, threads 128..255
        float* abase = out + (size_t)BATCH * CH * SEQ
                           + ((size_t)(b * SEQ + s0)) * SEQ;
#pragma unroll
        for (int i = 0; i < 16; ++i) {
            int slot = i * 128 + r;
            int row  = slot >> 8;
            int i0   = (slot & 255) << 2;
            int d = i0 - (s0 + row - HALFW);
            float4 w4 = {0.f, 0.f, 0.f, 0.f};
            if (d > -4 && d < WIDTH) {
                const float* srow = &sc[row * SCS];
                if (d >= 0     && d     < WIDTH) w4.x = srow[d];
                if (d + 1 >= 0 && d + 1 < WIDTH) w4.y = srow[d + 1];
                if (d + 2 >= 0 && d + 2 < WIDTH) w4.z = srow[d + 2];
                if (d + 3 >= 0 && d + 3 < WIDTH) w4.w = srow[d + 3];
            }
            *reinterpret_cast<float4*>(&abase[(size_t)row * SEQ + i0]) = w4;
        }
    }
    __syncthreads();

    // ---- v store: out[b][c][s0+sl], 8-lane segments of 32B per c-row ----
    float* vbase = out + ((size_t)b * CH) * SEQ + s0;
#pragma unroll
    for (int i = 0; i < 2; ++i) {
        int idx = i * 256 + tid;
        int c = idx >> 3, sl2 = idx & 7;
        vbase[(size_t)c * SEQ + sl2] = vt[sl2 * VTS + c];
    }
}

extern "C" void kernel_launch(void* const* d_in, const int* in_sizes, int n_in,
                              void* d_out, int out_size, void* d_ws, size_t ws_size,
                              hipStream_t stream) {
    const float* x    = (const float*)d_in[0];
    const float* Wt   = (const float*)d_in[1];
    const float* Wx   = (const float*)d_in[2];
    const float* Wa_w = (const float*)d_in[3];
    const float* Wa_b = (const float*)d_in[4];
    const float* bh   = (const float*)d_in[5];
    float* out = (float*)d_out;

    float* q  = (float*)d_ws;                      // (B, U, S), bh folded
    float* kk = q + (size_t)BATCH * UNITS * SEQ;   // (B, U, S)

    qk_kernel<<<BATCH * UNITS, 256, 0, stream>>>(x, Wt, Wx, bh, q, kk);
    attn_kernel<<<BATCH * (SEQ / TS), 256, 0, stream>>>(x, q, kk, Wa_w, Wa_b, out);
}